// Round 8
// baseline (251.608 us; speedup 1.0000x reference)
//
#include <hip/hip_runtime.h>
#include <hip/hip_bf16.h>

#define T_DIM 4096
#define B_DIM 32
#define I_DIM 512
#define O_DIM 512
#define M_DIM (T_DIM * B_DIM)   // 131072
#define PARAM 0.1f
#define ISCALE 1.1111112f       // 1/(1-p)

#define STRIP 64
#define TAPS 8                  // p^8 = 1e-8 << bf16 eps

#define BM 128
#define BN 128
#define BK 64
#define NK (I_DIM / BK)         // 8

typedef __attribute__((ext_vector_type(8))) short bf16x8;
typedef __attribute__((ext_vector_type(4))) float f32x4;

__device__ __forceinline__ unsigned short f2bf(float f) {
    union { __hip_bfloat16 b; unsigned short u; } cv;
    cv.b = __float2bfloat16(f);
    return cv.u;
}

// --- W fp32 -> bf16 (0.5 MB, ws offset 0) ---
__global__ __launch_bounds__(256) void wcvt_kernel(const float* __restrict__ W,
                                                   unsigned short* __restrict__ Wb) {
    const int i = (blockIdx.x * 256 + threadIdx.x) * 4;
    f32x4 v = *(const f32x4*)(W + i);
    ushort4 o;
    o.x = f2bf(v[0]); o.y = f2bf(v[1]); o.z = f2bf(v[2]); o.w = f2bf(v[3]);
    *(ushort4*)(Wb + i) = o;
}

// --- EMA over raw X (linearity: EMA(XW+b) = EMA(X)W + s[t]*b). Strip-parallel,
// TAPS warm-up reads raw X; bf16 output compacted into d_ws. ---
__global__ __launch_bounds__(256) void xema_kernel(const float* __restrict__ X,
                                                   unsigned short* __restrict__ Xv) {
    const int s   = blockIdx.x >> 4;                 // strip 0..63
    const int blk = blockIdx.x & 15;
    const int col = (blk * 256 + threadIdx.x) * 4;
    const int t0  = s * STRIP;
    const int b   = col >> 9;
    const int o   = col & 511;

    const float* xin = X + (size_t)t0 * 16384 + col;
    unsigned short* xout = Xv + (size_t)(t0 * 32 + b) * 512 + o;

    f32x4 v = {0.f, 0.f, 0.f, 0.f};
    if (s > 0) {
        const float* w = xin - (size_t)TAPS * 16384;
        #pragma unroll
        for (int j = 0; j < TAPS; ++j)
            v = PARAM * v + *(const f32x4*)(w + (size_t)j * 16384);
    }

    f32x4 bufA[8], bufB[8];
    #pragma unroll
    for (int j = 0; j < 8; ++j) bufA[j] = *(const f32x4*)(xin + (size_t)j * 16384);

    #pragma unroll
    for (int i = 0; i < STRIP; i += 16) {
        #pragma unroll
        for (int j = 0; j < 8; ++j)
            bufB[j] = *(const f32x4*)(xin + (size_t)(i + 8 + j) * 16384);
        #pragma unroll
        for (int j = 0; j < 8; ++j) {
            v = PARAM * v + bufA[j];
            ushort4 pk; pk.x = f2bf(v[0]); pk.y = f2bf(v[1]); pk.z = f2bf(v[2]); pk.w = f2bf(v[3]);
            *(ushort4*)(xout + (size_t)(i + j) * 16384) = pk;
        }
        if (i + 16 < STRIP) {
            #pragma unroll
            for (int j = 0; j < 8; ++j)
                bufA[j] = *(const f32x4*)(xin + (size_t)(i + 16 + j) * 16384);
        }
        #pragma unroll
        for (int j = 0; j < 8; ++j) {
            v = PARAM * v + bufB[j];
            ushort4 pk; pk.x = f2bf(v[0]); pk.y = f2bf(v[1]); pk.z = f2bf(v[2]); pk.w = f2bf(v[3]);
            *(ushort4*)(xout + (size_t)(i + 8 + j) * 16384) = pk;
        }
    }
}

// --- GEMM: 128x128 tile, BK=64, 2-buffer counted-vmcnt pipeline, 64KB LDS ->
// 2 blocks/CU (4 waves/SIMD): two independent block contexts cover each other's
// stalls (m97/m114 mechanism) AND the vmcnt never drains the in-flight prefetch.
// 8 waves, wave-tile 64x32 (acc 4x2). Pre-swizzled global_load_lds staging
// (involution c^(r&7)); swizzled ds_read; T5 setprio around MFMA clusters. ---
__global__ __launch_bounds__(512, 4) void gemm_kernel(const unsigned short* __restrict__ Xv,
                                                      const unsigned short* __restrict__ Wb,
                                                      const float* __restrict__ bias,
                                                      float* __restrict__ Y) {
    __shared__ __align__(16) short As[2][BM * BK];   // 16 KB x2
    __shared__ __align__(16) short Bs[2][BN * BK];   // 16 KB x2

    const int tid  = threadIdx.x;
    const int lane = tid & 63;
    const int wave = tid >> 6;        // 0..7
    const int wm   = wave >> 2;       // 0..1 (64-row half)
    const int wn   = wave & 3;        // 0..3 (32-col quarter)

    // 4096 blocks: xcd = bid&7; all 4 bn of one mt run temporally close on one
    // XCD -> A panel HBM-fetched once, L2-served 4x; W (512KB) stays L2-hot.
    const int bid = blockIdx.x;
    const int j   = bid >> 3;                     // 0..511
    const int bn  = j & 3;
    const int mt  = (bid & 7) * 128 + (j >> 2);   // 0..1023
    const int row0 = mt * BM;
    const int col0 = bn * BN;

    // Staging: 16B chunks, 8 per 128B row; rows covered in 2 sets of 64.
    // r&7 = (tid>>3)&7 for both sets -> swizzled source chunk is per-thread const.
    const int cs = (tid & 7) ^ ((tid >> 3) & 7);
    const unsigned short* aSrc = Xv + (size_t)(row0 + (tid >> 3)) * 512 + cs * 8;
    const unsigned short* bSrc = Wb + (size_t)(col0 + (tid >> 3)) * 512 + cs * 8;

    // 4 global_load_lds per thread per stage (A:2 sets, B:2 sets).
    // LDS dest for set s is linear: short-offset s*4096 + tid*8 (= wave-uniform
    // base + lane*16B as required).
    #define STAGE(buf, k0)                                                            \
        do {                                                                          \
            _Pragma("unroll")                                                         \
            for (int s_ = 0; s_ < 2; ++s_)                                            \
                __builtin_amdgcn_global_load_lds(                                     \
                    (const __attribute__((address_space(1))) unsigned int*)(aSrc + (size_t)s_ * 64 * 512 + (k0)), \
                    (__attribute__((address_space(3))) unsigned int*)(&As[buf][0] + s_ * 4096 + tid * 8),         \
                    16, 0, 0);                                                        \
            _Pragma("unroll")                                                         \
            for (int s_ = 0; s_ < 2; ++s_)                                            \
                __builtin_amdgcn_global_load_lds(                                     \
                    (const __attribute__((address_space(1))) unsigned int*)(bSrc + (size_t)s_ * 64 * 512 + (k0)), \
                    (__attribute__((address_space(3))) unsigned int*)(&Bs[buf][0] + s_ * 4096 + tid * 8),         \
                    16, 0, 0);                                                        \
        } while (0)

    f32x4 acc[4][2] = {};

    #define COMPUTE(buf)                                                              \
        do {                                                                          \
            _Pragma("unroll")                                                         \
            for (int kk = 0; kk < 2; ++kk) {                                          \
                const int cc = kk * 4 + (lane >> 4);                                  \
                bf16x8 a_[4], b_[2];                                                  \
                _Pragma("unroll")                                                     \
                for (int mf = 0; mf < 4; ++mf) {                                      \
                    const int r = wm * 64 + mf * 16 + (lane & 15);                    \
                    a_[mf] = *(const bf16x8*)((const char*)&As[buf][0] + r * 128 + ((cc ^ (r & 7)) << 4)); \
                }                                                                     \
                _Pragma("unroll")                                                     \
                for (int nf = 0; nf < 2; ++nf) {                                      \
                    const int r = wn * 32 + nf * 16 + (lane & 15);                    \
                    b_[nf] = *(const bf16x8*)((const char*)&Bs[buf][0] + r * 128 + ((cc ^ (r & 7)) << 4)); \
                }                                                                     \
                __builtin_amdgcn_s_setprio(1);                                        \
                _Pragma("unroll")                                                     \
                for (int mf = 0; mf < 4; ++mf)                                        \
                    _Pragma("unroll")                                                 \
                    for (int nf = 0; nf < 2; ++nf)                                    \
                        acc[mf][nf] = __builtin_amdgcn_mfma_f32_16x16x32_bf16(        \
                            a_[mf], b_[nf], acc[mf][nf], 0, 0, 0);                    \
                __builtin_amdgcn_s_setprio(0);                                        \
            }                                                                         \
        } while (0)

    // Iter: stage NEXT tile into the other buffer, wait only for the PREVIOUS
    // stage (counted vmcnt -> the 4 just-issued loads stay in flight across
    // both barriers), compute current.
    #define KITER(k, vm, dostage)                                                     \
        do {                                                                          \
            if (dostage) STAGE(((k) & 1) ^ 1, ((k) + 1) * BK);                        \
            asm volatile("s_waitcnt vmcnt(" #vm ")" ::: "memory");                    \
            __builtin_amdgcn_sched_barrier(0);                                        \
            __builtin_amdgcn_s_barrier();                                             \
            asm volatile("" ::: "memory");                                            \
            COMPUTE((k) & 1);                                                         \
            asm volatile("" ::: "memory");                                            \
            __builtin_amdgcn_s_barrier();                                             \
            asm volatile("" ::: "memory");                                            \
        } while (0)

    STAGE(0, 0);
    KITER(0, 4, 1);
    KITER(1, 4, 1);
    KITER(2, 4, 1);
    KITER(3, 4, 1);
    KITER(4, 4, 1);
    KITER(5, 4, 1);
    KITER(6, 4, 1);
    KITER(7, 0, 0);

    // bias EMA-scale s[t] = (1 - p^(t+1))/(1-p); t depends on (mf, j) only.
    float sc[4][4];
    #pragma unroll
    for (int mf = 0; mf < 4; ++mf)
        #pragma unroll
        for (int jj = 0; jj < 4; ++jj) {
            const int t = (row0 + wm * 64 + mf * 16 + ((lane >> 4) << 2) + jj) >> 5;
            sc[mf][jj] = (1.0f - __expf(-2.3025851f * (float)(t + 1))) * ISCALE;
        }

    #pragma unroll
    for (int mf = 0; mf < 4; ++mf) {
        #pragma unroll
        for (int nf = 0; nf < 2; ++nf) {
            const int gcol = col0 + wn * 32 + nf * 16 + (lane & 15);
            const float bv = bias[gcol];
            #pragma unroll
            for (int jj = 0; jj < 4; ++jj) {
                const int grow = row0 + wm * 64 + mf * 16 + ((lane >> 4) << 2) + jj;
                Y[(size_t)grow * O_DIM + gcol] = acc[mf][nf][jj] + sc[mf][jj] * bv;
            }
        }
    }
}

extern "C" void kernel_launch(void* const* d_in, const int* in_sizes, int n_in,
                              void* d_out, int out_size, void* d_ws, size_t ws_size,
                              hipStream_t stream) {
    const float* X    = (const float*)d_in[0];
    const float* W    = (const float*)d_in[1];
    const float* bias = (const float*)d_in[2];
    float* Y = (float*)d_out;
    unsigned short* Wb = (unsigned short*)d_ws;                       // 512 KB
    unsigned short* Xv = (unsigned short*)((char*)d_ws + (1 << 20));  // 134 MB

    wcvt_kernel<<<dim3(O_DIM * I_DIM / (256 * 4)), dim3(256), 0, stream>>>(W, Wb);
    xema_kernel<<<dim3((T_DIM / STRIP) * 16), dim3(256), 0, stream>>>(X, Xv);
    gemm_kernel<<<dim3((M_DIM / BM) * (O_DIM / BN)), dim3(512), 0, stream>>>(Xv, Wb, bias, Y);
}

// Round 9
// 236.510 us; speedup vs baseline: 1.0638x; 1.0638x over previous
//
#include <hip/hip_runtime.h>
#include <hip/hip_bf16.h>

#define T_DIM 4096
#define B_DIM 32
#define I_DIM 512
#define O_DIM 512
#define M_DIM (T_DIM * B_DIM)   // 131072
#define PARAM 0.1f
#define ISCALE 1.1111112f       // 1/(1-p)

#define STRIP 32
#define TAPS 8                  // p^8 = 1e-8 << bf16 eps

#define BM 128
#define BN 128
#define BK 64
#define NK (I_DIM / BK)         // 8

typedef __attribute__((ext_vector_type(8))) short bf16x8;
typedef __attribute__((ext_vector_type(4))) float f32x4;

__device__ __forceinline__ unsigned short f2bf(float f) {
    union { __hip_bfloat16 b; unsigned short u; } cv;
    cv.b = __float2bfloat16(f);
    return cv.u;
}

// --- W fp32 -> bf16 (0.5 MB, ws offset 0) ---
__global__ __launch_bounds__(256) void wcvt_kernel(const float* __restrict__ W,
                                                   unsigned short* __restrict__ Wb) {
    const int i = (blockIdx.x * 256 + threadIdx.x) * 4;
    f32x4 v = *(const f32x4*)(W + i);
    ushort4 o;
    o.x = f2bf(v[0]); o.y = f2bf(v[1]); o.z = f2bf(v[2]); o.w = f2bf(v[3]);
    *(ushort4*)(Wb + i) = o;
}

// --- EMA over raw X (linearity: EMA(XW+b) = EMA(X)W + s[t]*b). STRIP=32 ->
// 2048 blocks (8 waves/SIMD) so TLP hides HBM latency; slim 4+4-row double
// buffer keeps VGPR <= 64 for full occupancy. bf16 output into d_ws. ---
__global__ __launch_bounds__(256) void xema_kernel(const float* __restrict__ X,
                                                   unsigned short* __restrict__ Xv) {
    const int s   = blockIdx.x >> 4;                 // strip 0..127
    const int blk = blockIdx.x & 15;
    const int col = (blk * 256 + threadIdx.x) * 4;
    const int t0  = s * STRIP;
    const int b   = col >> 9;
    const int o   = col & 511;

    const float* xin = X + (size_t)t0 * 16384 + col;
    unsigned short* xout = Xv + (size_t)(t0 * 32 + b) * 512 + o;

    f32x4 v = {0.f, 0.f, 0.f, 0.f};
    if (s > 0) {
        const float* w = xin - (size_t)TAPS * 16384;
        #pragma unroll
        for (int j = 0; j < TAPS; ++j)
            v = PARAM * v + *(const f32x4*)(w + (size_t)j * 16384);
    }

    f32x4 bufA[4], bufB[4];
    #pragma unroll
    for (int j = 0; j < 4; ++j) bufA[j] = *(const f32x4*)(xin + (size_t)j * 16384);

    #pragma unroll
    for (int i = 0; i < STRIP; i += 8) {
        #pragma unroll
        for (int j = 0; j < 4; ++j)
            bufB[j] = *(const f32x4*)(xin + (size_t)(i + 4 + j) * 16384);
        #pragma unroll
        for (int j = 0; j < 4; ++j) {
            v = PARAM * v + bufA[j];
            ushort4 pk; pk.x = f2bf(v[0]); pk.y = f2bf(v[1]); pk.z = f2bf(v[2]); pk.w = f2bf(v[3]);
            *(ushort4*)(xout + (size_t)(i + j) * 16384) = pk;
        }
        if (i + 8 < STRIP) {
            #pragma unroll
            for (int j = 0; j < 4; ++j)
                bufA[j] = *(const f32x4*)(xin + (size_t)(i + 8 + j) * 16384);
        }
        #pragma unroll
        for (int j = 0; j < 4; ++j) {
            v = PARAM * v + bufB[j];
            ushort4 pk; pk.x = f2bf(v[0]); pk.y = f2bf(v[1]); pk.z = f2bf(v[2]); pk.w = f2bf(v[3]);
            *(ushort4*)(xout + (size_t)(i + 4 + j) * 16384) = pk;
        }
    }
}

// --- GEMM: m97 replica. 256 threads / 4 waves, 128x128 tile, BK=64, wave-tile
// 64x64 (acc 4x4 -> 2 MFMA per KB of LDS reads), single-buffer 32KB LDS ->
// 4 blocks/CU: inter-block context overlap (m114) hides the per-block
// stage/drain/store phases. Plain 2-barrier loop. Pre-swizzled global_load_lds
// staging (involution c^(r&7)); swizzled ds_read. ---
__global__ __launch_bounds__(256, 4) void gemm_kernel(const unsigned short* __restrict__ Xv,
                                                      const unsigned short* __restrict__ Wb,
                                                      const float* __restrict__ bias,
                                                      float* __restrict__ Y) {
    __shared__ __align__(16) short As[BM * BK];   // 16 KB
    __shared__ __align__(16) short Bs[BN * BK];   // 16 KB

    const int tid  = threadIdx.x;
    const int lane = tid & 63;
    const int wave = tid >> 6;        // 0..3
    const int wm   = wave >> 1;       // 0..1
    const int wn   = wave & 1;        // 0..1

    // 4096 blocks: xcd = bid&7; all 4 bn of one mt run temporally close on one
    // XCD -> A panel HBM-fetched once, L2-served 4x; W (512KB) stays L2-hot.
    const int bid = blockIdx.x;
    const int j   = bid >> 3;                     // 0..511
    const int bn  = j & 3;
    const int mt  = (bid & 7) * 128 + (j >> 2);   // 0..1023
    const int row0 = mt * BM;
    const int col0 = bn * BN;

    // Staging: 16B chunks, 8 per 128B row; 4 sets of 32 rows. r&7 = (tid>>3)&7
    // for every set -> swizzled source chunk cs is per-thread constant.
    const int cs = (tid & 7) ^ ((tid >> 3) & 7);
    const unsigned short* aSrc = Xv + (size_t)(row0 + (tid >> 3)) * 512 + cs * 8;
    const unsigned short* bSrc = Wb + (size_t)(col0 + (tid >> 3)) * 512 + cs * 8;

    f32x4 acc[4][4] = {};

    for (int ks = 0; ks < NK; ++ks) {
        const int k0 = ks * BK;
        #pragma unroll
        for (int s_ = 0; s_ < 4; ++s_)
            __builtin_amdgcn_global_load_lds(
                (const __attribute__((address_space(1))) unsigned int*)(aSrc + (size_t)s_ * 32 * 512 + k0),
                (__attribute__((address_space(3))) unsigned int*)(As + (s_ * 256 + tid) * 8),
                16, 0, 0);
        #pragma unroll
        for (int s_ = 0; s_ < 4; ++s_)
            __builtin_amdgcn_global_load_lds(
                (const __attribute__((address_space(1))) unsigned int*)(bSrc + (size_t)s_ * 32 * 512 + k0),
                (__attribute__((address_space(3))) unsigned int*)(Bs + (s_ * 256 + tid) * 8),
                16, 0, 0);
        __syncthreads();

        #pragma unroll
        for (int kk = 0; kk < 2; ++kk) {
            const int cc = kk * 4 + (lane >> 4);
            bf16x8 a_[4], b_[4];
            #pragma unroll
            for (int mf = 0; mf < 4; ++mf) {
                const int r = wm * 64 + mf * 16 + (lane & 15);
                a_[mf] = *(const bf16x8*)((const char*)As + r * 128 + ((cc ^ (r & 7)) << 4));
            }
            #pragma unroll
            for (int nf = 0; nf < 4; ++nf) {
                const int r = wn * 64 + nf * 16 + (lane & 15);
                b_[nf] = *(const bf16x8*)((const char*)Bs + r * 128 + ((cc ^ (r & 7)) << 4));
            }
            #pragma unroll
            for (int mf = 0; mf < 4; ++mf)
                #pragma unroll
                for (int nf = 0; nf < 4; ++nf)
                    acc[mf][nf] = __builtin_amdgcn_mfma_f32_16x16x32_bf16(
                        a_[mf], b_[nf], acc[mf][nf], 0, 0, 0);
        }
        __syncthreads();
    }

    // bias EMA-scale s[t] = (1 - p^(t+1))/(1-p); t depends on (mf, j) only.
    float sc[4][4];
    #pragma unroll
    for (int mf = 0; mf < 4; ++mf)
        #pragma unroll
        for (int jj = 0; jj < 4; ++jj) {
            const int t = (row0 + wm * 64 + mf * 16 + ((lane >> 4) << 2) + jj) >> 5;
            sc[mf][jj] = (1.0f - __expf(-2.3025851f * (float)(t + 1))) * ISCALE;
        }

    #pragma unroll
    for (int mf = 0; mf < 4; ++mf) {
        #pragma unroll
        for (int nf = 0; nf < 4; ++nf) {
            const int gcol = col0 + wn * 64 + nf * 16 + (lane & 15);
            const float bv = bias[gcol];
            #pragma unroll
            for (int jj = 0; jj < 4; ++jj) {
                const int grow = row0 + wm * 64 + mf * 16 + ((lane >> 4) << 2) + jj;
                Y[(size_t)grow * O_DIM + gcol] = acc[mf][nf][jj] + sc[mf][jj] * bv;
            }
        }
    }
}

extern "C" void kernel_launch(void* const* d_in, const int* in_sizes, int n_in,
                              void* d_out, int out_size, void* d_ws, size_t ws_size,
                              hipStream_t stream) {
    const float* X    = (const float*)d_in[0];
    const float* W    = (const float*)d_in[1];
    const float* bias = (const float*)d_in[2];
    float* Y = (float*)d_out;
    unsigned short* Wb = (unsigned short*)d_ws;                       // 512 KB
    unsigned short* Xv = (unsigned short*)((char*)d_ws + (1 << 20));  // 134 MB

    wcvt_kernel<<<dim3(O_DIM * I_DIM / (256 * 4)), dim3(256), 0, stream>>>(W, Wb);
    xema_kernel<<<dim3((T_DIM / STRIP) * 16), dim3(256), 0, stream>>>(X, Xv);
    gemm_kernel<<<dim3((M_DIM / BM) * (O_DIM / BN)), dim3(256), 0, stream>>>(Xv, Wb, bias, Y);
}